// Round 2
// baseline (1060.563 us; speedup 1.0000x reference)
//
#include <hip/hip_runtime.h>

#define IN_DIM 512
#define HID_DIM 256
#define ROWS 64        // rows per tile (2 MFMA row-blocks)
#define XSS 520        // shorts per xs row; pad spreads banks, keeps b128 alignment
#define PSEG 8         // partials per segment (512 blocks -> 2/CU, all resident)
#define PSTRIDE 516    // floats per partial record: O[512], M, d, pad

typedef __bf16 bf16x8 __attribute__((ext_vector_type(8)));
typedef unsigned short ushort8 __attribute__((ext_vector_type(8)));
typedef float floatx16 __attribute__((ext_vector_type(16)));

__device__ __forceinline__ unsigned short f2bf_rne(float x) {
    unsigned int u = __float_as_uint(x);
    u += 0x7FFFu + ((u >> 16) & 1u);
    return (unsigned short)(u >> 16);
}
__device__ __forceinline__ unsigned int pack_bf2(float lo, float hi) {
    const unsigned int u0 = __float_as_uint(lo) + 0x8000u;
    const unsigned int u1 = __float_as_uint(hi) + 0x8000u;
    return __builtin_amdgcn_perm(u1, u0, 0x07060302u);
}
// branchless erf-based GELU (A&S 7.1.26, |eps|<=1.5e-7)
__device__ __forceinline__ float gelu(float x) {
    const float ax = fabsf(x) * 0.70710678118654752f;
    const float t = __builtin_amdgcn_rcpf(1.0f + 0.3275911f * ax);
    const float y = t * (0.254829592f +
                    t * (-0.284496736f +
                    t * (1.421413741f +
                    t * (-1.453152027f + t * 1.061405429f))));
    const float e = __expf(-ax * ax);
    float er = 1.0f - y * e;
    er = __builtin_copysignf(er, x);
    return 0.5f * x * (1.0f + er);
}

// barrier WITHOUT the __syncthreads vmcnt(0) drain: LDS ordering only.
// Outstanding global (vmcnt) loads legally stay in flight across s_barrier
// (HK 8-phase pattern). lgkmcnt(0) makes this wave's ds_writes visible before
// the barrier; sched_barrier(0) pins ordering around the inline asm (rule #18).
__device__ __forceinline__ void barrier_nodrain() {
    asm volatile("s_waitcnt lgkmcnt(0)" ::: "memory");
    __builtin_amdgcn_sched_barrier(0);
    __builtin_amdgcn_s_barrier();
    __builtin_amdgcn_sched_barrier(0);
}

// ---------------- kernel 0: fold ln_g/ln_b into w1 ----------------
__global__ void prep_w1_kernel(const float* __restrict__ w1, const float* __restrict__ ln_g,
                               const float* __restrict__ ln_b, const float* __restrict__ b1,
                               unsigned short* __restrict__ w1g, float* __restrict__ gw,
                               float* __restrict__ c1) {
    const int wid = threadIdx.x >> 6;
    const int lane = threadIdx.x & 63;
    const int h = blockIdx.x * 4 + wid;
    const int c8 = lane * 8;
    const float4 wv0 = *(const float4*)(w1 + (size_t)h * IN_DIM + c8);
    const float4 wv1 = *(const float4*)(w1 + (size_t)h * IN_DIM + c8 + 4);
    const float4 g0 = *(const float4*)(ln_g + c8);
    const float4 g1 = *(const float4*)(ln_g + c8 + 4);
    const float4 bb0 = *(const float4*)(ln_b + c8);
    const float4 bb1 = *(const float4*)(ln_b + c8 + 4);
    float wg[8] = {wv0.x * g0.x, wv0.y * g0.y, wv0.z * g0.z, wv0.w * g0.w,
                   wv1.x * g1.x, wv1.y * g1.y, wv1.z * g1.z, wv1.w * g1.w};
    float sg = wg[0] + wg[1] + wg[2] + wg[3] + wg[4] + wg[5] + wg[6] + wg[7];
    float sb = wv0.x * bb0.x + wv0.y * bb0.y + wv0.z * bb0.z + wv0.w * bb0.w +
               wv1.x * bb1.x + wv1.y * bb1.y + wv1.z * bb1.z + wv1.w * bb1.w;
    ushort8 outv;
#pragma unroll
    for (int j = 0; j < 8; j++) outv[j] = f2bf_rne(wg[j]);
    *(ushort8*)(w1g + (size_t)h * IN_DIM + c8) = outv;
    for (int m = 32; m; m >>= 1) {
        sg += __shfl_xor(sg, m);
        sb += __shfl_xor(sb, m);
    }
    if (lane == 0) {
        gw[h] = sg;
        c1[h] = sb + b1[h];
    }
}

// ---------------- kernel 1: fused score + online-softmax pooling ----------------
// One WG = 512 threads (8 waves) owns a contiguous slice of one segment.
// Per 64-row tile: consume reg-prefetched half-tile + issue/consume second half
// -> stats + bf16 LDS tile; MFMA GEMM (each wave ONE 32-hid B slice, ring-8 B
// prefetch from L2, BOTH 32-row halves); epilogue -> spart; prefetch next
// tile's first half into regs (stays in flight across the RAW barriers);
// replicated per-wave online-softmax (M,D in registers); pool O += w*f.
// Barriers: B1 = __syncthreads (no VMEM outstanding there, drain is free);
// B2/B4 = raw s_barrier + lgkmcnt only, so the prefetch is never drained.
__global__ __launch_bounds__(512, 4) void fused_kernel(
    const float* __restrict__ feats, const unsigned short* __restrict__ w1g,
    const float* __restrict__ gw, const float* __restrict__ c1,
    const float* __restrict__ w2, const float* __restrict__ b2,
    const int* __restrict__ offsets, float* __restrict__ partials, int N) {
    __shared__ unsigned short xs[ROWS][XSS];
    __shared__ float spart[8][ROWS];
    __shared__ float2 stats_s[ROWS];

    const int tid = threadIdx.x;
    const int wid = tid >> 6;      // 0..7 -> hid slice
    const int lane = tid & 63;
    const int l31 = lane & 31;
    const int hi = lane >> 5;      // 0/1
    const int seg = blockIdx.x / PSEG;
    const int part = blockIdx.x % PSEG;
    const int st = offsets[seg];
    const int en = offsets[seg + 1];
    const int len = en - st;
    const int chunk = (len + PSEG - 1) / PSEG;
    const int rs = st + part * chunk;
    const int re = min(rs + chunk, en);
    const int nt = (re > rs) ? ((re - rs + ROWS - 1) / ROWS) : 0;

    // one 32-hid slice per wave
    const int hid = wid * 32 + l31;
    const float gw0 = gw[hid];
    const float c10 = c1[hid];
    const float w20 = w2[hid];
    const float b2v = b2[0];

    // stage mapping: 16 threads per row, 32 floats each (strided float4);
    // 512 threads cover a 32-row half-tile per pass
    const int srow = tid >> 4;    // 0..31
    const int sc = tid & 15;      // 0..15

    float O = 0.0f;               // pooled column tid
    float Mreg = -3.0e38f, Dreg = 0.0f;

    // ---- prologue: prefetch first half of tile 0 into registers ----
    float4 f[8];
    if (nt > 0) {
        int rg = rs + srow;
        if (rg > N - 1) rg = N - 1;
        const float* fp = feats + (size_t)rg * IN_DIM + sc * 4;
#pragma unroll
        for (int j = 0; j < 8; j++) f[j] = *(const float4*)(fp + j * 64);
    }

    for (int t = 0; t < nt; t++) {
        const int row0 = rs + t * ROWS;

        // ---- issue second-half loads (latency hides under half-1 processing) --
        float4 g[8];
        {
            int rg = row0 + 32 + srow;
            if (rg > N - 1) rg = N - 1;
            const float* fp = feats + (size_t)rg * IN_DIM + sc * 4;
#pragma unroll
            for (int j = 0; j < 8; j++) g[j] = *(const float4*)(fp + j * 64);
        }

        // ---- stage half 1 from prefetched regs: stats + bf16 pack -> LDS ----
        {
            float sf = 0.0f, qf = 0.0f;
#pragma unroll
            for (int j = 0; j < 8; j++) {
                sf += f[j].x + f[j].y + f[j].z + f[j].w;
                qf = fmaf(f[j].x, f[j].x, qf);
                qf = fmaf(f[j].y, f[j].y, qf);
                qf = fmaf(f[j].z, f[j].z, qf);
                qf = fmaf(f[j].w, f[j].w, qf);
            }
#pragma unroll
            for (int j = 0; j < 8; j++) {
                uint2 pk;
                pk.x = pack_bf2(f[j].x, f[j].y);
                pk.y = pack_bf2(f[j].z, f[j].w);
                *(uint2*)&xs[srow][sc * 4 + j * 64] = pk;
            }
            sf += __shfl_xor(sf, 1); qf += __shfl_xor(qf, 1);
            sf += __shfl_xor(sf, 2); qf += __shfl_xor(qf, 2);
            sf += __shfl_xor(sf, 4); qf += __shfl_xor(qf, 4);
            sf += __shfl_xor(sf, 8); qf += __shfl_xor(qf, 8);
            if (sc == 0) {
                const float mu = sf * (1.0f / IN_DIM);
                const float var = fmaxf(qf * (1.0f / IN_DIM) - mu * mu, 0.0f);
                stats_s[srow] = make_float2(mu, rsqrtf(var + 1e-5f));
            }
        }
        // ---- stage half 2 ----
        {
            float sf = 0.0f, qf = 0.0f;
#pragma unroll
            for (int j = 0; j < 8; j++) {
                sf += g[j].x + g[j].y + g[j].z + g[j].w;
                qf = fmaf(g[j].x, g[j].x, qf);
                qf = fmaf(g[j].y, g[j].y, qf);
                qf = fmaf(g[j].z, g[j].z, qf);
                qf = fmaf(g[j].w, g[j].w, qf);
            }
#pragma unroll
            for (int j = 0; j < 8; j++) {
                uint2 pk;
                pk.x = pack_bf2(g[j].x, g[j].y);
                pk.y = pack_bf2(g[j].z, g[j].w);
                *(uint2*)&xs[32 + srow][sc * 4 + j * 64] = pk;
            }
            sf += __shfl_xor(sf, 1); qf += __shfl_xor(qf, 1);
            sf += __shfl_xor(sf, 2); qf += __shfl_xor(qf, 2);
            sf += __shfl_xor(sf, 4); qf += __shfl_xor(qf, 4);
            sf += __shfl_xor(sf, 8); qf += __shfl_xor(qf, 8);
            if (sc == 0) {
                const float mu = sf * (1.0f / IN_DIM);
                const float var = fmaxf(qf * (1.0f / IN_DIM) - mu * mu, 0.0f);
                stats_s[32 + srow] = make_float2(mu, rsqrtf(var + 1e-5f));
            }
        }
        __syncthreads();  // B1: xs + stats ready (no VMEM outstanding here)

        // ---- GEMM: A (2 row-halves) from LDS, B slice via ring-8 from L2 ----
        floatx16 acc0 = (floatx16)(0.0f);
        floatx16 acc1 = (floatx16)(0.0f);
        {
            const unsigned short* bp = w1g + (size_t)hid * IN_DIM + hi * 8;
            const unsigned short* ap0 = &xs[l31][hi * 8];
            const unsigned short* ap1 = &xs[32 + l31][hi * 8];
            ushort8 br[8];
#pragma unroll
            for (int i = 0; i < 8; i++) br[i] = *(const ushort8*)(bp + i * 16);
#pragma unroll
            for (int kg = 0; kg < 4; kg++) {
#pragma unroll
                for (int u = 0; u < 8; u++) {
                    const int ki = kg * 8 + u;
                    const bf16x8 a0 = __builtin_bit_cast(bf16x8, *(const ushort8*)(ap0 + ki * 16));
                    const bf16x8 a1 = __builtin_bit_cast(bf16x8, *(const ushort8*)(ap1 + ki * 16));
                    const bf16x8 bv = __builtin_bit_cast(bf16x8, br[u]);
                    acc0 = __builtin_amdgcn_mfma_f32_32x32x16_bf16(a0, bv, acc0, 0, 0, 0);
                    acc1 = __builtin_amdgcn_mfma_f32_32x32x16_bf16(a1, bv, acc1, 0, 0, 0);
                    if (ki + 8 < 32)
                        br[u] = *(const ushort8*)(bp + (ki + 8) * 16);
                }
            }
        }

        // ---- epilogue: LN affine + GELU + w2; butterfly over 32 hid lanes ----
        {
            float tv[16];
#pragma unroll
            for (int q = 0; q < 16; q++) {
                const int rowl = (q & 3) + 8 * (q >> 2) + 4 * hi;
                const float2 stt = stats_s[rowl];
                const float h = stt.y * (acc0[q] - stt.x * gw0) + c10;
                tv[q] = gelu(h) * w20;
            }
#pragma unroll
            for (int m = 1; m < 32; m <<= 1)
#pragma unroll
                for (int q = 0; q < 16; q++) tv[q] += __shfl_xor(tv[q], m);
            if (l31 == 0) {
#pragma unroll
                for (int q = 0; q < 16; q++)
                    spart[wid][(q & 3) + 8 * (q >> 2) + 4 * hi] = tv[q];
            }
#pragma unroll
            for (int q = 0; q < 16; q++) {
                const int rowl = 32 + (q & 3) + 8 * (q >> 2) + 4 * hi;
                const float2 stt = stats_s[rowl];
                const float h = stt.y * (acc1[q] - stt.x * gw0) + c10;
                tv[q] = gelu(h) * w20;
            }
#pragma unroll
            for (int m = 1; m < 32; m <<= 1)
#pragma unroll
                for (int q = 0; q < 16; q++) tv[q] += __shfl_xor(tv[q], m);
            if (l31 == 0) {
#pragma unroll
                for (int q = 0; q < 16; q++)
                    spart[wid][32 + (q & 3) + 8 * (q >> 2) + 4 * hi] = tv[q];
            }
        }

        // ---- prefetch next tile's first half (issued AFTER all B loads, so
        // GEMM vmcnt FIFO is clean; stays in flight across the raw barriers) --
        if (t + 1 < nt) {
            int rg = row0 + ROWS + srow;
            if (rg > N - 1) rg = N - 1;
            const float* fp = feats + (size_t)rg * IN_DIM + sc * 4;
#pragma unroll
            for (int j = 0; j < 8; j++) f[j] = *(const float4*)(fp + j * 64);
        }
        barrier_nodrain();  // B2: spart ready; prefetch NOT drained

        // ---- replicated online-softmax (all 8 waves compute identical M,D,w) --
        float wv_, al;
        {
            float sv = spart[0][lane] + spart[1][lane] + spart[2][lane] + spart[3][lane] +
                       spart[4][lane] + spart[5][lane] + spart[6][lane] + spart[7][lane] + b2v;
            if (row0 + lane >= re) sv = -3.0e38f;
            float mt = sv;
#pragma unroll
            for (int m = 1; m < 64; m <<= 1) mt = fmaxf(mt, __shfl_xor(mt, m));
            const float Mnew = fmaxf(Mreg, mt);
            al = __expf(Mreg - Mnew);
            wv_ = __expf(sv - Mnew);
            float ws = wv_;
#pragma unroll
            for (int m = 1; m < 64; m <<= 1) ws += __shfl_xor(ws, m);
            Dreg = Dreg * al + ws;
            Mreg = Mnew;
        }

        // ---- pool accumulate: thread owns column tid ----
        O *= al;
#pragma unroll 16
        for (int rr = 0; rr < ROWS; rr++) {
            const float wr = __shfl(wv_, rr);
            const unsigned int us = (unsigned int)xs[rr][tid];
            O = fmaf(wr, __uint_as_float(us << 16), O);
        }
        if (t + 1 < nt) barrier_nodrain();  // B4: xs free; prefetch NOT drained
    }

    float* pp = partials + (size_t)blockIdx.x * PSTRIDE;
    pp[tid] = O;
    if (tid == 0) {
        pp[512] = Mreg;
        pp[513] = Dreg;
    }
}

// ---------------- kernel 2: combine partials per segment ----------------
__global__ void combine_kernel(const float* __restrict__ partials, float* __restrict__ out) {
    const int seg = blockIdx.x;
    const int t = threadIdx.x;  // 256 threads, 2 cols each
    const float* base = partials + (size_t)seg * PSEG * PSTRIDE;
    float M = -3.0e38f;
#pragma unroll
    for (int p = 0; p < PSEG; p++) M = fmaxf(M, base[p * PSTRIDE + 512]);
    float D = 0.0f, a0 = 0.0f, a1 = 0.0f;
#pragma unroll
    for (int p = 0; p < PSEG; p++) {
        const float e = __expf(base[p * PSTRIDE + 512] - M);
        D += e * base[p * PSTRIDE + 513];
        a0 += e * base[p * PSTRIDE + 2 * t];
        a1 += e * base[p * PSTRIDE + 2 * t + 1];
    }
    out[(size_t)seg * IN_DIM + 2 * t] = a0 / D;
    out[(size_t)seg * IN_DIM + 2 * t + 1] = a1 / D;
}

extern "C" void kernel_launch(void* const* d_in, const int* in_sizes, int n_in,
                              void* d_out, int out_size, void* d_ws, size_t ws_size,
                              hipStream_t stream) {
    const float* feats = (const float*)d_in[0];
    const float* ln_g = (const float*)d_in[1];
    const float* ln_b = (const float*)d_in[2];
    const float* w1 = (const float*)d_in[3];
    const float* b1 = (const float*)d_in[4];
    const float* w2 = (const float*)d_in[5];
    const float* b2 = (const float*)d_in[6];
    const int* offsets = (const int*)d_in[7];
    const int N = in_sizes[0] / IN_DIM;
    const int nseg = in_sizes[7] - 1;
    float* out = (float*)d_out;

    // ws: [w1g bf16 256K][gw 1K][c1 1K][partials nseg*PSEG*PSTRIDE*4]
    char* ws = (char*)d_ws;
    unsigned short* w1g = (unsigned short*)ws;
    float* gw = (float*)(ws + (size_t)HID_DIM * IN_DIM * 2);
    float* c1 = gw + HID_DIM;
    float* partials = c1 + HID_DIM;

    prep_w1_kernel<<<HID_DIM / 4, 256, 0, stream>>>(w1, ln_g, ln_b, b1, w1g, gw, c1);
    fused_kernel<<<nseg * PSEG, 512, 0, stream>>>(feats, w1g, gw, c1, w2, b2, offsets,
                                                  partials, N);
    combine_kernel<<<nseg, 256, 0, stream>>>(partials, out);
}

// Round 3
// 985.517 us; speedup vs baseline: 1.0761x; 1.0761x over previous
//
#include <hip/hip_runtime.h>

#define IN_DIM 512
#define HID_DIM 256
#define ROWS 64        // rows per tile (2 MFMA row-blocks)
#define XSS 520        // shorts per xs row; pad spreads banks, keeps b128 alignment
#define PSEG 8         // partials per segment (512 blocks -> 2/CU, all resident)
#define PSTRIDE 516    // floats per partial record: O[512], M, d, pad

typedef __bf16 bf16x8 __attribute__((ext_vector_type(8)));
typedef unsigned short ushort8 __attribute__((ext_vector_type(8)));
typedef float floatx16 __attribute__((ext_vector_type(16)));

__device__ __forceinline__ unsigned short f2bf_rne(float x) {
    unsigned int u = __float_as_uint(x);
    u += 0x7FFFu + ((u >> 16) & 1u);
    return (unsigned short)(u >> 16);
}
__device__ __forceinline__ unsigned int pack_bf2(float lo, float hi) {
    const unsigned int u0 = __float_as_uint(lo) + 0x8000u;
    const unsigned int u1 = __float_as_uint(hi) + 0x8000u;
    return __builtin_amdgcn_perm(u1, u0, 0x07060302u);
}
// branchless erf-based GELU (A&S 7.1.26, |eps|<=1.5e-7)
__device__ __forceinline__ float gelu(float x) {
    const float ax = fabsf(x) * 0.70710678118654752f;
    const float t = __builtin_amdgcn_rcpf(1.0f + 0.3275911f * ax);
    const float y = t * (0.254829592f +
                    t * (-0.284496736f +
                    t * (1.421413741f +
                    t * (-1.453152027f + t * 1.061405429f))));
    const float e = __expf(-ax * ax);
    float er = 1.0f - y * e;
    er = __builtin_copysignf(er, x);
    return 0.5f * x * (1.0f + er);
}

// barrier WITHOUT the __syncthreads vmcnt(0) drain: LDS ordering only.
// Outstanding global (vmcnt) loads legally stay in flight across s_barrier
// (HK 8-phase pattern). lgkmcnt(0) makes this wave's ds ops visible/complete
// before the barrier; sched_barrier(0) pins ordering around the asm (rule #18).
__device__ __forceinline__ void barrier_nodrain() {
    asm volatile("s_waitcnt lgkmcnt(0)" ::: "memory");
    __builtin_amdgcn_sched_barrier(0);
    __builtin_amdgcn_s_barrier();
    __builtin_amdgcn_sched_barrier(0);
}

// ---------------- kernel 0: fold ln_g/ln_b into w1 ----------------
__global__ void prep_w1_kernel(const float* __restrict__ w1, const float* __restrict__ ln_g,
                               const float* __restrict__ ln_b, const float* __restrict__ b1,
                               unsigned short* __restrict__ w1g, float* __restrict__ gw,
                               float* __restrict__ c1) {
    const int wid = threadIdx.x >> 6;
    const int lane = threadIdx.x & 63;
    const int h = blockIdx.x * 4 + wid;
    const int c8 = lane * 8;
    const float4 wv0 = *(const float4*)(w1 + (size_t)h * IN_DIM + c8);
    const float4 wv1 = *(const float4*)(w1 + (size_t)h * IN_DIM + c8 + 4);
    const float4 g0 = *(const float4*)(ln_g + c8);
    const float4 g1 = *(const float4*)(ln_g + c8 + 4);
    const float4 bb0 = *(const float4*)(ln_b + c8);
    const float4 bb1 = *(const float4*)(ln_b + c8 + 4);
    float wg[8] = {wv0.x * g0.x, wv0.y * g0.y, wv0.z * g0.z, wv0.w * g0.w,
                   wv1.x * g1.x, wv1.y * g1.y, wv1.z * g1.z, wv1.w * g1.w};
    float sg = wg[0] + wg[1] + wg[2] + wg[3] + wg[4] + wg[5] + wg[6] + wg[7];
    float sb = wv0.x * bb0.x + wv0.y * bb0.y + wv0.z * bb0.z + wv0.w * bb0.w +
               wv1.x * bb1.x + wv1.y * bb1.y + wv1.z * bb1.z + wv1.w * bb1.w;
    ushort8 outv;
#pragma unroll
    for (int j = 0; j < 8; j++) outv[j] = f2bf_rne(wg[j]);
    *(ushort8*)(w1g + (size_t)h * IN_DIM + c8) = outv;
    for (int m = 32; m; m >>= 1) {
        sg += __shfl_xor(sg, m);
        sb += __shfl_xor(sb, m);
    }
    if (lane == 0) {
        gw[h] = sg;
        c1[h] = sb + b1[h];
    }
}

// ---------------- kernel 1: fused score + online-softmax pooling ----------------
// One WG = 512 threads (8 waves) owns a contiguous slice of one segment.
// Per 64-row tile: stage in FOUR 16-row quarters (16 VGPR each, 3-deep reg
// pipeline: Q1,Q2 in flight while Q0 processes) -> stats + bf16 LDS tile;
// MFMA GEMM (each wave ONE 32-hid B slice via ring-8 L2 prefetch, BOTH 32-row
// halves); epilogue -> spart; prefetch ONLY next tile's Q0 (16 regs) across
// the raw barriers; replicated per-wave online-softmax; pool O += w*f.
// Register budget: peak ~60 live (GEMM: 32 acc + 16 ring + addr). LDS caps
// occupancy at 2 blocks/CU = 4 waves/EU, so waves_per_eu(4,4) pins the
// allocator at the 128-VGPR bucket — round-2's spill-to-scratch (406 MB
// scratch writes at VGPR=64) must not reappear.
__global__ __launch_bounds__(512)
__attribute__((amdgpu_waves_per_eu(4, 4))) void fused_kernel(
    const float* __restrict__ feats, const unsigned short* __restrict__ w1g,
    const float* __restrict__ gw, const float* __restrict__ c1,
    const float* __restrict__ w2, const float* __restrict__ b2,
    const int* __restrict__ offsets, float* __restrict__ partials, int N) {
    __shared__ unsigned short xs[ROWS][XSS];
    __shared__ float spart[8][ROWS];
    __shared__ float2 stats_s[ROWS];

    const int tid = threadIdx.x;
    const int wid = tid >> 6;      // 0..7 -> hid slice
    const int lane = tid & 63;
    const int l31 = lane & 31;
    const int hi = lane >> 5;      // 0/1
    const int seg = blockIdx.x / PSEG;
    const int part = blockIdx.x % PSEG;
    const int st = offsets[seg];
    const int en = offsets[seg + 1];
    const int len = en - st;
    const int chunk = (len + PSEG - 1) / PSEG;
    const int rs = st + part * chunk;
    const int re = min(rs + chunk, en);
    const int nt = (re > rs) ? ((re - rs + ROWS - 1) / ROWS) : 0;

    // one 32-hid slice per wave
    const int hid = wid * 32 + l31;
    const float gw0 = gw[hid];
    const float c10 = c1[hid];
    const float w20 = w2[hid];
    const float b2v = b2[0];

    // stage mapping: 32 threads per row, 16 floats each; 512 threads = 16 rows
    const int srow = tid >> 5;    // 0..15 (quarter-local row)
    const int sc = tid & 31;      // 0..31

    float O = 0.0f;               // pooled column tid
    float Mreg = -3.0e38f, Dreg = 0.0f;

    // issue one quarter's loads (16 VGPRs): absolute row base rowq
    auto issue = [&](float4 (&v)[4], int rowq) {
        int rg = rowq + srow;
        if (rg > N - 1) rg = N - 1;
        const float* fp = feats + (size_t)rg * IN_DIM + sc * 4;
#pragma unroll
        for (int j = 0; j < 4; j++) v[j] = *(const float4*)(fp + j * 128);
    };
    // consume one quarter: stats + bf16 pack -> LDS rows [lrow0, lrow0+16)
    auto process = [&](const float4 (&v)[4], int lrow0) {
        float sf = 0.0f, qf = 0.0f;
#pragma unroll
        for (int j = 0; j < 4; j++) {
            sf += v[j].x + v[j].y + v[j].z + v[j].w;
            qf = fmaf(v[j].x, v[j].x, qf);
            qf = fmaf(v[j].y, v[j].y, qf);
            qf = fmaf(v[j].z, v[j].z, qf);
            qf = fmaf(v[j].w, v[j].w, qf);
        }
#pragma unroll
        for (int j = 0; j < 4; j++) {
            uint2 pk;
            pk.x = pack_bf2(v[j].x, v[j].y);
            pk.y = pack_bf2(v[j].z, v[j].w);
            *(uint2*)&xs[lrow0 + srow][sc * 4 + j * 128] = pk;
        }
        sf += __shfl_xor(sf, 1);  qf += __shfl_xor(qf, 1);
        sf += __shfl_xor(sf, 2);  qf += __shfl_xor(qf, 2);
        sf += __shfl_xor(sf, 4);  qf += __shfl_xor(qf, 4);
        sf += __shfl_xor(sf, 8);  qf += __shfl_xor(qf, 8);
        sf += __shfl_xor(sf, 16); qf += __shfl_xor(qf, 16);
        if (sc == 0) {
            const float mu = sf * (1.0f / IN_DIM);
            const float var = fmaxf(qf * (1.0f / IN_DIM) - mu * mu, 0.0f);
            stats_s[lrow0 + srow] = make_float2(mu, rsqrtf(var + 1e-5f));
        }
    };

    // ---- prologue: prefetch tile-0 Q0 ----
    float4 f[4], g[4], h[4];
    if (nt > 0) issue(f, rs);

    for (int t = 0; t < nt; t++) {
        const int row0 = rs + t * ROWS;

        // ---- stage: 3-deep quarter pipeline (<=48 VGPRs of staging live) ----
        issue(g, row0 + 16);   // Q1
        issue(h, row0 + 32);   // Q2
        process(f, 0);         // Q0
        issue(f, row0 + 48);   // Q3 (f free after process)
        process(g, 16);        // Q1
        process(h, 32);        // Q2
        process(f, 48);        // Q3
        __syncthreads();  // B1: xs + stats ready (no VMEM outstanding: drain free)

        // ---- GEMM: A (2 row-halves) from LDS, B slice via ring-8 from L2 ----
        floatx16 acc0 = (floatx16)(0.0f);
        floatx16 acc1 = (floatx16)(0.0f);
        {
            const unsigned short* bp = w1g + (size_t)hid * IN_DIM + hi * 8;
            const unsigned short* ap0 = &xs[l31][hi * 8];
            const unsigned short* ap1 = &xs[32 + l31][hi * 8];
            ushort8 br[8];
#pragma unroll
            for (int i = 0; i < 8; i++) br[i] = *(const ushort8*)(bp + i * 16);
#pragma unroll
            for (int kg = 0; kg < 4; kg++) {
#pragma unroll
                for (int u = 0; u < 8; u++) {
                    const int ki = kg * 8 + u;
                    const bf16x8 a0 = __builtin_bit_cast(bf16x8, *(const ushort8*)(ap0 + ki * 16));
                    const bf16x8 a1 = __builtin_bit_cast(bf16x8, *(const ushort8*)(ap1 + ki * 16));
                    const bf16x8 bv = __builtin_bit_cast(bf16x8, br[u]);
                    acc0 = __builtin_amdgcn_mfma_f32_32x32x16_bf16(a0, bv, acc0, 0, 0, 0);
                    acc1 = __builtin_amdgcn_mfma_f32_32x32x16_bf16(a1, bv, acc1, 0, 0, 0);
                    if (ki + 8 < 32)
                        br[u] = *(const ushort8*)(bp + (ki + 8) * 16);
                }
            }
        }

        // ---- epilogue: LN affine + GELU + w2; butterfly over 32 hid lanes ----
        {
            float tv[16];
#pragma unroll
            for (int q = 0; q < 16; q++) {
                const int rowl = (q & 3) + 8 * (q >> 2) + 4 * hi;
                const float2 stt = stats_s[rowl];
                const float hh = stt.y * (acc0[q] - stt.x * gw0) + c10;
                tv[q] = gelu(hh) * w20;
            }
#pragma unroll
            for (int m = 1; m < 32; m <<= 1)
#pragma unroll
                for (int q = 0; q < 16; q++) tv[q] += __shfl_xor(tv[q], m);
            if (l31 == 0) {
#pragma unroll
                for (int q = 0; q < 16; q++)
                    spart[wid][(q & 3) + 8 * (q >> 2) + 4 * hi] = tv[q];
            }
#pragma unroll
            for (int q = 0; q < 16; q++) {
                const int rowl = 32 + (q & 3) + 8 * (q >> 2) + 4 * hi;
                const float2 stt = stats_s[rowl];
                const float hh = stt.y * (acc1[q] - stt.x * gw0) + c10;
                tv[q] = gelu(hh) * w20;
            }
#pragma unroll
            for (int m = 1; m < 32; m <<= 1)
#pragma unroll
                for (int q = 0; q < 16; q++) tv[q] += __shfl_xor(tv[q], m);
            if (l31 == 0) {
#pragma unroll
                for (int q = 0; q < 16; q++)
                    spart[wid][32 + (q & 3) + 8 * (q >> 2) + 4 * hi] = tv[q];
            }
        }

        // ---- prefetch next tile's Q0 only (16 regs live across raw barriers;
        // issued AFTER all B loads so the GEMM's vmcnt FIFO stayed clean) ----
        if (t + 1 < nt) issue(f, row0 + ROWS);
        barrier_nodrain();  // B2: spart ready; prefetch NOT drained

        // ---- replicated online-softmax (all 8 waves compute identical M,D,w) --
        float wv_, al;
        {
            float sv = spart[0][lane] + spart[1][lane] + spart[2][lane] + spart[3][lane] +
                       spart[4][lane] + spart[5][lane] + spart[6][lane] + spart[7][lane] + b2v;
            if (row0 + lane >= re) sv = -3.0e38f;
            float mt = sv;
#pragma unroll
            for (int m = 1; m < 64; m <<= 1) mt = fmaxf(mt, __shfl_xor(mt, m));
            const float Mnew = fmaxf(Mreg, mt);
            al = __expf(Mreg - Mnew);
            wv_ = __expf(sv - Mnew);
            float ws = wv_;
#pragma unroll
            for (int m = 1; m < 64; m <<= 1) ws += __shfl_xor(ws, m);
            Dreg = Dreg * al + ws;
            Mreg = Mnew;
        }

        // ---- pool accumulate: thread owns column tid ----
        O *= al;
#pragma unroll 16
        for (int rr = 0; rr < ROWS; rr++) {
            const float wr = __shfl(wv_, rr);
            const unsigned int us = (unsigned int)xs[rr][tid];
            O = fmaf(wr, __uint_as_float(us << 16), O);
        }
        if (t + 1 < nt) barrier_nodrain();  // B4: xs free; prefetch NOT drained
    }

    float* pp = partials + (size_t)blockIdx.x * PSTRIDE;
    pp[tid] = O;
    if (tid == 0) {
        pp[512] = Mreg;
        pp[513] = Dreg;
    }
}

// ---------------- kernel 2: combine partials per segment ----------------
__global__ void combine_kernel(const float* __restrict__ partials, float* __restrict__ out) {
    const int seg = blockIdx.x;
    const int t = threadIdx.x;  // 256 threads, 2 cols each
    const float* base = partials + (size_t)seg * PSEG * PSTRIDE;
    float M = -3.0e38f;
#pragma unroll
    for (int p = 0; p < PSEG; p++) M = fmaxf(M, base[p * PSTRIDE + 512]);
    float D = 0.0f, a0 = 0.0f, a1 = 0.0f;
#pragma unroll
    for (int p = 0; p < PSEG; p++) {
        const float e = __expf(base[p * PSTRIDE + 512] - M);
        D += e * base[p * PSTRIDE + 513];
        a0 += e * base[p * PSTRIDE + 2 * t];
        a1 += e * base[p * PSTRIDE + 2 * t + 1];
    }
    out[(size_t)seg * IN_DIM + 2 * t] = a0 / D;
    out[(size_t)seg * IN_DIM + 2 * t + 1] = a1 / D;
}

extern "C" void kernel_launch(void* const* d_in, const int* in_sizes, int n_in,
                              void* d_out, int out_size, void* d_ws, size_t ws_size,
                              hipStream_t stream) {
    const float* feats = (const float*)d_in[0];
    const float* ln_g = (const float*)d_in[1];
    const float* ln_b = (const float*)d_in[2];
    const float* w1 = (const float*)d_in[3];
    const float* b1 = (const float*)d_in[4];
    const float* w2 = (const float*)d_in[5];
    const float* b2 = (const float*)d_in[6];
    const int* offsets = (const int*)d_in[7];
    const int N = in_sizes[0] / IN_DIM;
    const int nseg = in_sizes[7] - 1;
    float* out = (float*)d_out;

    // ws: [w1g bf16 256K][gw 1K][c1 1K][partials nseg*PSEG*PSTRIDE*4]
    char* ws = (char*)d_ws;
    unsigned short* w1g = (unsigned short*)ws;
    float* gw = (float*)(ws + (size_t)HID_DIM * IN_DIM * 2);
    float* c1 = gw + HID_DIM;
    float* partials = c1 + HID_DIM;

    prep_w1_kernel<<<HID_DIM / 4, 256, 0, stream>>>(w1, ln_g, ln_b, b1, w1g, gw, c1);
    fused_kernel<<<nseg * PSEG, 512, 0, stream>>>(feats, w1g, gw, c1, w2, b2, offsets,
                                                  partials, N);
    combine_kernel<<<nseg, 256, 0, stream>>>(partials, out);
}

// Round 4
// 963.938 us; speedup vs baseline: 1.1002x; 1.0224x over previous
//
#include <hip/hip_runtime.h>

#define IN_DIM 512
#define HID_DIM 256
#define ROWS 64        // rows per tile (2 MFMA row-blocks)
#define XSS 520        // shorts per xs row; pad spreads banks, keeps b128 alignment
#define PSEG 8         // partials per segment (512 blocks -> 2/CU, all resident)
#define PSTRIDE 516    // floats per partial record: O[512], M, d, pad

typedef __bf16 bf16x8 __attribute__((ext_vector_type(8)));
typedef unsigned short ushort8 __attribute__((ext_vector_type(8)));
typedef float floatx16 __attribute__((ext_vector_type(16)));

__device__ __forceinline__ unsigned short f2bf_rne(float x) {
    unsigned int u = __float_as_uint(x);
    u += 0x7FFFu + ((u >> 16) & 1u);
    return (unsigned short)(u >> 16);
}
__device__ __forceinline__ unsigned int pack_bf2(float lo, float hi) {
    const unsigned int u0 = __float_as_uint(lo) + 0x8000u;
    const unsigned int u1 = __float_as_uint(hi) + 0x8000u;
    return __builtin_amdgcn_perm(u1, u0, 0x07060302u);
}
// branchless erf-based GELU (A&S 7.1.26, |eps|<=1.5e-7)
__device__ __forceinline__ float gelu(float x) {
    const float ax = fabsf(x) * 0.70710678118654752f;
    const float t = __builtin_amdgcn_rcpf(1.0f + 0.3275911f * ax);
    const float y = t * (0.254829592f +
                    t * (-0.284496736f +
                    t * (1.421413741f +
                    t * (-1.453152027f + t * 1.061405429f))));
    const float e = __expf(-ax * ax);
    float er = 1.0f - y * e;
    er = __builtin_copysignf(er, x);
    return 0.5f * x * (1.0f + er);
}

// barrier WITHOUT the __syncthreads vmcnt(0) drain: LDS ordering only.
// Outstanding global (vmcnt) loads legally stay in flight across s_barrier
// (HK 8-phase pattern). lgkmcnt(0) completes this wave's ds ops before the
// barrier; sched_barrier(0) pins ordering around the asm (rule #18).
__device__ __forceinline__ void barrier_nodrain() {
    asm volatile("s_waitcnt lgkmcnt(0)" ::: "memory");
    __builtin_amdgcn_sched_barrier(0);
    __builtin_amdgcn_s_barrier();
    __builtin_amdgcn_sched_barrier(0);
}

// ---------------- kernel 0: fold ln_g/ln_b into w1 ----------------
__global__ void prep_w1_kernel(const float* __restrict__ w1, const float* __restrict__ ln_g,
                               const float* __restrict__ ln_b, const float* __restrict__ b1,
                               unsigned short* __restrict__ w1g, float* __restrict__ gw,
                               float* __restrict__ c1) {
    const int wid = threadIdx.x >> 6;
    const int lane = threadIdx.x & 63;
    const int h = blockIdx.x * 4 + wid;
    const int c8 = lane * 8;
    const float4 wv0 = *(const float4*)(w1 + (size_t)h * IN_DIM + c8);
    const float4 wv1 = *(const float4*)(w1 + (size_t)h * IN_DIM + c8 + 4);
    const float4 g0 = *(const float4*)(ln_g + c8);
    const float4 g1 = *(const float4*)(ln_g + c8 + 4);
    const float4 bb0 = *(const float4*)(ln_b + c8);
    const float4 bb1 = *(const float4*)(ln_b + c8 + 4);
    float wg[8] = {wv0.x * g0.x, wv0.y * g0.y, wv0.z * g0.z, wv0.w * g0.w,
                   wv1.x * g1.x, wv1.y * g1.y, wv1.z * g1.z, wv1.w * g1.w};
    float sg = wg[0] + wg[1] + wg[2] + wg[3] + wg[4] + wg[5] + wg[6] + wg[7];
    float sb = wv0.x * bb0.x + wv0.y * bb0.y + wv0.z * bb0.z + wv0.w * bb0.w +
               wv1.x * bb1.x + wv1.y * bb1.y + wv1.z * bb1.z + wv1.w * bb1.w;
    ushort8 outv;
#pragma unroll
    for (int j = 0; j < 8; j++) outv[j] = f2bf_rne(wg[j]);
    *(ushort8*)(w1g + (size_t)h * IN_DIM + c8) = outv;
    for (int m = 32; m; m >>= 1) {
        sg += __shfl_xor(sg, m);
        sb += __shfl_xor(sb, m);
    }
    if (lane == 0) {
        gw[h] = sg;
        c1[h] = sb + b1[h];
    }
}

// ---------------- kernel 1: fused score + online-softmax pooling ----------------
// One WG = 512 threads (8 waves) owns a contiguous slice of one segment.
// DESIGNED TO FIT 64 VGPRs (allocator ignores waves_per_eu hints; rounds 2/3
// spilled 150-400 MB to scratch). Peak live per phase kept ~<=52:
//  - stage: 2-deep 16-row-quarter pipeline (f,g = 32 regs)
//  - GEMM: the two 32-row halves run SEQUENTIALLY (acc 16 + ring-8 B 16);
//    B re-streamed from L2 per half (w1g is L2-resident, we're HBM-bound)
//  - pool: thread owns a column PAIR over a 32-row half (dword LDS reads);
//    halves merged once at kernel end through the spart buffer
// Cross-barrier prefetch of next tile's Q0+Q1 (32 regs) stays in flight
// through GEMM/softmax/pool via no-drain barriers: 16 waves/CU x 8 KB
// outstanding = 128 KB/CU >> the ~9 KB needed to saturate HBM.
__global__ __launch_bounds__(512, 4) void fused_kernel(
    const float* __restrict__ feats, const unsigned short* __restrict__ w1g,
    const float* __restrict__ gw, const float* __restrict__ c1,
    const float* __restrict__ w2, const float* __restrict__ b2,
    const int* __restrict__ offsets, float* __restrict__ partials, int N) {
    __shared__ unsigned short xs[ROWS][XSS];
    __shared__ float spart[8][ROWS];   // reused as 512-float merge buffer at end
    __shared__ float2 stats_s[ROWS];

    const int tid = threadIdx.x;
    const int wid = tid >> 6;      // 0..7 -> hid slice
    const int lane = tid & 63;
    const int l31 = lane & 31;
    const int hi = lane >> 5;      // 0/1
    const int seg = blockIdx.x / PSEG;
    const int part = blockIdx.x % PSEG;
    const int st = offsets[seg];
    const int en = offsets[seg + 1];
    const int len = en - st;
    const int chunk = (len + PSEG - 1) / PSEG;
    const int rs = st + part * chunk;
    const int re = min(rs + chunk, en);
    const int nt = (re > rs) ? ((re - rs + ROWS - 1) / ROWS) : 0;

    // one 32-hid slice per wave
    const int hid = wid * 32 + l31;
    const float gw0 = gw[hid];
    const float c10 = c1[hid];
    const float w20 = w2[hid];
    const float b2v = b2[0];

    // stage mapping: 32 threads per row, 16 floats each; 512 threads = 16 rows
    const int srow = tid >> 5;    // 0..15 (quarter-local row)
    const int sc = tid & 31;      // 0..31

    // pool mapping: thread owns cols (pc, pc+1) over rows [rhalf*32, rhalf*32+32)
    const int pc = (tid & 255) * 2;
    const int rhalf = tid >> 8;   // 0/1 (wave-uniform)

    float O0 = 0.0f, O1 = 0.0f;   // pooled column pair (this thread's row-half)
    float Mreg = -3.0e38f, Dreg = 0.0f;

    // issue one quarter's loads (16 VGPRs): absolute row base rowq
    auto issue = [&](float4 (&v)[4], int rowq) {
        int rg = rowq + srow;
        if (rg > N - 1) rg = N - 1;
        const float* fp = feats + (size_t)rg * IN_DIM + sc * 4;
#pragma unroll
        for (int j = 0; j < 4; j++) v[j] = *(const float4*)(fp + j * 128);
    };
    // consume one quarter: stats + bf16 pack -> LDS rows [lrow0, lrow0+16)
    auto process = [&](const float4 (&v)[4], int lrow0) {
        float sf = 0.0f, qf = 0.0f;
#pragma unroll
        for (int j = 0; j < 4; j++) {
            sf += v[j].x + v[j].y + v[j].z + v[j].w;
            qf = fmaf(v[j].x, v[j].x, qf);
            qf = fmaf(v[j].y, v[j].y, qf);
            qf = fmaf(v[j].z, v[j].z, qf);
            qf = fmaf(v[j].w, v[j].w, qf);
        }
#pragma unroll
        for (int j = 0; j < 4; j++) {
            uint2 pk;
            pk.x = pack_bf2(v[j].x, v[j].y);
            pk.y = pack_bf2(v[j].z, v[j].w);
            *(uint2*)&xs[lrow0 + srow][sc * 4 + j * 128] = pk;
        }
        sf += __shfl_xor(sf, 1);  qf += __shfl_xor(qf, 1);
        sf += __shfl_xor(sf, 2);  qf += __shfl_xor(qf, 2);
        sf += __shfl_xor(sf, 4);  qf += __shfl_xor(qf, 4);
        sf += __shfl_xor(sf, 8);  qf += __shfl_xor(qf, 8);
        sf += __shfl_xor(sf, 16); qf += __shfl_xor(qf, 16);
        if (sc == 0) {
            const float mu = sf * (1.0f / IN_DIM);
            const float var = fmaxf(qf * (1.0f / IN_DIM) - mu * mu, 0.0f);
            stats_s[lrow0 + srow] = make_float2(mu, rsqrtf(var + 1e-5f));
        }
    };

    // ---- prologue: prefetch tile-0 Q0+Q1 ----
    float4 f[4], g[4];
    if (nt > 0) {
        issue(f, rs);
        issue(g, rs + 16);
    }

    for (int t = 0; t < nt; t++) {
        const int row0 = rs + t * ROWS;

        // ---- stage: 2-deep quarter pipeline (32 VGPRs of staging live) ----
        process(f, 0);            // Q0 (in flight since previous pool phase)
        issue(f, row0 + 32);      // Q2
        process(g, 16);           // Q1 (in flight since previous pool phase)
        issue(g, row0 + 48);      // Q3
        process(f, 32);           // Q2
        process(g, 48);           // Q3
        __syncthreads();  // B1: xs + stats ready (no VMEM outstanding: drain free)

        // ---- GEMM + epilogue, one 32-row half at a time (acc 16 + ring 16) ----
#pragma unroll 1
        for (int h2 = 0; h2 < 2; ++h2) {
            floatx16 acc = (floatx16)(0.0f);
            {
                const unsigned short* bp = w1g + (size_t)hid * IN_DIM + hi * 8;
                const unsigned short* ap = &xs[h2 * 32 + l31][hi * 8];
                ushort8 br[8];
#pragma unroll
                for (int i = 0; i < 8; i++) br[i] = *(const ushort8*)(bp + i * 16);
#pragma unroll
                for (int kg = 0; kg < 4; kg++) {
#pragma unroll
                    for (int u = 0; u < 8; u++) {
                        const int ki = kg * 8 + u;
                        const bf16x8 a =
                            __builtin_bit_cast(bf16x8, *(const ushort8*)(ap + ki * 16));
                        const bf16x8 bv = __builtin_bit_cast(bf16x8, br[u]);
                        acc = __builtin_amdgcn_mfma_f32_32x32x16_bf16(a, bv, acc, 0, 0, 0);
                        if (ki + 8 < 32)
                            br[u] = *(const ushort8*)(bp + (ki + 8) * 16);
                    }
                }
            }
            // epilogue: LN affine + GELU + w2; butterfly over 32 hid lanes
            float tv[16];
#pragma unroll
            for (int q = 0; q < 16; q++) {
                const int rowl = h2 * 32 + (q & 3) + 8 * (q >> 2) + 4 * hi;
                const float2 stt = stats_s[rowl];
                const float hh = stt.y * (acc[q] - stt.x * gw0) + c10;
                tv[q] = gelu(hh) * w20;
            }
#pragma unroll
            for (int m = 1; m < 32; m <<= 1)
#pragma unroll
                for (int q = 0; q < 16; q++) tv[q] += __shfl_xor(tv[q], m);
            if (l31 == 0) {
#pragma unroll
                for (int q = 0; q < 16; q++)
                    spart[wid][h2 * 32 + (q & 3) + 8 * (q >> 2) + 4 * hi] = tv[q];
            }
        }

        // ---- prefetch next tile's Q0+Q1 (32 regs, in flight across the raw
        // barriers and the whole softmax+pool phase; GEMM vmcnt FIFO was clean) --
        if (t + 1 < nt) {
            issue(f, row0 + ROWS);
            issue(g, row0 + ROWS + 16);
        }
        barrier_nodrain();  // B2: spart ready; prefetch NOT drained

        // ---- replicated online-softmax (all 8 waves compute identical M,D,w) --
        float wv_, al;
        {
            float sv = spart[0][lane] + spart[1][lane] + spart[2][lane] + spart[3][lane] +
                       spart[4][lane] + spart[5][lane] + spart[6][lane] + spart[7][lane] + b2v;
            if (row0 + lane >= re) sv = -3.0e38f;
            float mt = sv;
#pragma unroll
            for (int m = 1; m < 64; m <<= 1) mt = fmaxf(mt, __shfl_xor(mt, m));
            const float Mnew = fmaxf(Mreg, mt);
            al = __expf(Mreg - Mnew);
            wv_ = __expf(sv - Mnew);
            float ws = wv_;
#pragma unroll
            for (int m = 1; m < 64; m <<= 1) ws += __shfl_xor(ws, m);
            Dreg = Dreg * al + ws;
            Mreg = Mnew;
        }

        // ---- pool accumulate: column pair (pc,pc+1), rows [rhalf*32, +32) ----
        O0 *= al;
        O1 *= al;
#pragma unroll 8
        for (int r = 0; r < 32; r++) {
            const int rr = rhalf * 32 + r;
            const float wr = __shfl(wv_, rr);
            const unsigned int d = *(const unsigned int*)&xs[rr][pc];
            O0 = fmaf(wr, __uint_as_float(d << 16), O0);
            O1 = fmaf(wr, __uint_as_float(d & 0xffff0000u), O1);
        }
        if (t + 1 < nt) barrier_nodrain();  // B4: xs free; prefetch NOT drained
    }

    // ---- merge the two row-halves through LDS, write partials ----
    __syncthreads();
    float* mrg = (float*)spart;
    if (rhalf == 1) {
        mrg[pc] = O0;
        mrg[pc + 1] = O1;
    }
    __syncthreads();
    float* pp = partials + (size_t)blockIdx.x * PSTRIDE;
    if (rhalf == 0) {
        pp[pc] = O0 + mrg[pc];
        pp[pc + 1] = O1 + mrg[pc + 1];
    }
    if (tid == 0) {
        pp[512] = Mreg;
        pp[513] = Dreg;
    }
}

// ---------------- kernel 2: combine partials per segment ----------------
__global__ void combine_kernel(const float* __restrict__ partials, float* __restrict__ out) {
    const int seg = blockIdx.x;
    const int t = threadIdx.x;  // 256 threads, 2 cols each
    const float* base = partials + (size_t)seg * PSEG * PSTRIDE;
    float M = -3.0e38f;
#pragma unroll
    for (int p = 0; p < PSEG; p++) M = fmaxf(M, base[p * PSTRIDE + 512]);
    float D = 0.0f, a0 = 0.0f, a1 = 0.0f;
#pragma unroll
    for (int p = 0; p < PSEG; p++) {
        const float e = __expf(base[p * PSTRIDE + 512] - M);
        D += e * base[p * PSTRIDE + 513];
        a0 += e * base[p * PSTRIDE + 2 * t];
        a1 += e * base[p * PSTRIDE + 2 * t + 1];
    }
    out[(size_t)seg * IN_DIM + 2 * t] = a0 / D;
    out[(size_t)seg * IN_DIM + 2 * t + 1] = a1 / D;
}

extern "C" void kernel_launch(void* const* d_in, const int* in_sizes, int n_in,
                              void* d_out, int out_size, void* d_ws, size_t ws_size,
                              hipStream_t stream) {
    const float* feats = (const float*)d_in[0];
    const float* ln_g = (const float*)d_in[1];
    const float* ln_b = (const float*)d_in[2];
    const float* w1 = (const float*)d_in[3];
    const float* b1 = (const float*)d_in[4];
    const float* w2 = (const float*)d_in[5];
    const float* b2 = (const float*)d_in[6];
    const int* offsets = (const int*)d_in[7];
    const int N = in_sizes[0] / IN_DIM;
    const int nseg = in_sizes[7] - 1;
    float* out = (float*)d_out;

    // ws: [w1g bf16 256K][gw 1K][c1 1K][partials nseg*PSEG*PSTRIDE*4]
    char* ws = (char*)d_ws;
    unsigned short* w1g = (unsigned short*)ws;
    float* gw = (float*)(ws + (size_t)HID_DIM * IN_DIM * 2);
    float* c1 = gw + HID_DIM;
    float* partials = c1 + HID_DIM;

    prep_w1_kernel<<<HID_DIM / 4, 256, 0, stream>>>(w1, ln_g, ln_b, b1, w1g, gw, c1);
    fused_kernel<<<nseg * PSEG, 512, 0, stream>>>(feats, w1g, gw, c1, w2, b2, offsets,
                                                  partials, N);
    combine_kernel<<<nseg, 256, 0, stream>>>(partials, out);
}